// Round 2
// baseline (11708.635 us; speedup 1.0000x reference)
//
#include <hip/hip_runtime.h>
#include <cstddef>

// Problem constants (fixed by the reference)
constexpr int N_ = 100000;   // nodes
constexpr int E_ = 1600000;  // edges (= 3125 * 512 exactly)
constexpr int G_ = 128;      // graphs
#define SLOPE 0.15f

__device__ __forceinline__ float leaky(float v) { return v > 0.0f ? v : SLOPE * v; }

// ---------------------------------------------------------------------------
// Edge kernel: fused edge MLPs for BOTH convs (they depend only on edge_attr),
// 2 edges per thread (each LDS weight read feeds 8 FMAs), scatter-add into
// agg1/agg2 with fp32 atomics. Also accumulates target degree.
// ---------------------------------------------------------------------------
__device__ __forceinline__ void conv_pair(
    const float* __restrict__ sWbase,   // LDS: w1[32][64], b1[64], w2[64][64], b2[64]
    const float* __restrict__ ea0, const float* __restrict__ ea1,
    float* __restrict__ aggp0, float* __restrict__ aggp1)
{
    const float* w1 = sWbase;
    const float* b1 = sWbase + 2048;
    const float* w2 = sWbase + 2112;
    const float* b2 = sWbase + 6208;

    float ta[64], tb[64];
#pragma unroll
    for (int j = 0; j < 64; j += 4) {
        float a0 = b1[j], a1 = b1[j + 1], a2 = b1[j + 2], a3 = b1[j + 3];
        float c0 = a0, c1 = a1, c2 = a2, c3 = a3;
#pragma unroll
        for (int k = 0; k < 32; k++) {
            float4 w = *reinterpret_cast<const float4*>(&w1[k * 64 + j]);
            float e0 = ea0[k], e1 = ea1[k];
            a0 += e0 * w.x; a1 += e0 * w.y; a2 += e0 * w.z; a3 += e0 * w.w;
            c0 += e1 * w.x; c1 += e1 * w.y; c2 += e1 * w.z; c3 += e1 * w.w;
        }
        ta[j] = leaky(a0); ta[j + 1] = leaky(a1); ta[j + 2] = leaky(a2); ta[j + 3] = leaky(a3);
        tb[j] = leaky(c0); tb[j + 1] = leaky(c1); tb[j + 2] = leaky(c2); tb[j + 3] = leaky(c3);
    }
#pragma unroll
    for (int j = 0; j < 64; j += 4) {
        float a0 = b2[j], a1 = b2[j + 1], a2 = b2[j + 2], a3 = b2[j + 3];
        float c0 = a0, c1 = a1, c2 = a2, c3 = a3;
#pragma unroll
        for (int k = 0; k < 64; k++) {
            float4 w = *reinterpret_cast<const float4*>(&w2[k * 64 + j]);
            float t0 = ta[k], t1 = tb[k];
            a0 += t0 * w.x; a1 += t0 * w.y; a2 += t0 * w.z; a3 += t0 * w.w;
            c0 += t1 * w.x; c1 += t1 * w.y; c2 += t1 * w.z; c3 += t1 * w.w;
        }
        atomicAdd(&aggp0[j],     a0);
        atomicAdd(&aggp0[j + 1], a1);
        atomicAdd(&aggp0[j + 2], a2);
        atomicAdd(&aggp0[j + 3], a3);
        atomicAdd(&aggp1[j],     c0);
        atomicAdd(&aggp1[j + 1], c1);
        atomicAdd(&aggp1[j + 2], c2);
        atomicAdd(&aggp1[j + 3], c3);
    }
}

__global__ __launch_bounds__(256) void edge_kernel(
    const float* __restrict__ edge_attr, const int* __restrict__ ei,
    const float* __restrict__ e1w1, const float* __restrict__ e1b1,
    const float* __restrict__ e1w2, const float* __restrict__ e1b2,
    const float* __restrict__ e2w1, const float* __restrict__ e2b1,
    const float* __restrict__ e2w2, const float* __restrict__ e2b2,
    float* __restrict__ agg1, float* __restrict__ agg2, float* __restrict__ deg)
{
    __shared__ __align__(16) float sW[2 * 6272];
    // layout per conv c (base = c*6272): w1 [32][64] @0, b1 @2048, w2 [64][64] @2112, b2 @6208
    for (int t = threadIdx.x; t < 2048; t += 256) sW[t]         = e1w1[t];
    for (int t = threadIdx.x; t < 64;   t += 256) sW[2048 + t]  = e1b1[t];
    for (int t = threadIdx.x; t < 4096; t += 256) sW[2112 + t]  = e1w2[t];
    for (int t = threadIdx.x; t < 64;   t += 256) sW[6208 + t]  = e1b2[t];
    for (int t = threadIdx.x; t < 2048; t += 256) sW[6272 + t]  = e2w1[t];
    for (int t = threadIdx.x; t < 64;   t += 256) sW[8320 + t]  = e2b1[t];
    for (int t = threadIdx.x; t < 4096; t += 256) sW[8384 + t]  = e2w2[t];
    for (int t = threadIdx.x; t < 64;   t += 256) sW[12480 + t] = e2b2[t];
    __syncthreads();

    int e0 = blockIdx.x * 512 + threadIdx.x;   // grid: E_/512 blocks exactly
    int e1 = e0 + 256;

    int tg0 = ei[E_ + e0];   // edge_index row 1 = target
    int tg1 = ei[E_ + e1];
    atomicAdd(&deg[tg0], 1.0f);
    atomicAdd(&deg[tg1], 1.0f);

    float ea0[32], ea1[32];
    {
        const float4* p0 = reinterpret_cast<const float4*>(edge_attr + (size_t)e0 * 32);
        const float4* p1 = reinterpret_cast<const float4*>(edge_attr + (size_t)e1 * 32);
#pragma unroll
        for (int r = 0; r < 8; r++) {
            float4 v = p0[r];
            ea0[4 * r] = v.x; ea0[4 * r + 1] = v.y; ea0[4 * r + 2] = v.z; ea0[4 * r + 3] = v.w;
            float4 u = p1[r];
            ea1[4 * r] = u.x; ea1[4 * r + 1] = u.y; ea1[4 * r + 2] = u.z; ea1[4 * r + 3] = u.w;
        }
    }

    conv_pair(&sW[0],    ea0, ea1, agg1 + (size_t)tg0 * 64, agg1 + (size_t)tg1 * 64);
    conv_pair(&sW[6272], ea0, ea1, agg2 + (size_t)tg0 * 64, agg2 + (size_t)tg1 * 64);
}

// ---------------------------------------------------------------------------
// Node update conv1: h1 = leaky(deg*(x@A + b) + agg1@B), written IN PLACE over
// agg1 (each thread fully reads its row before storing).
//   n1w is [128,64] row-major: rows 0..63 = A (node part), 64..127 = B (emb)
// ---------------------------------------------------------------------------
__global__ __launch_bounds__(256) void node1_kernel(
    const float* __restrict__ x, float* __restrict__ agg1,
    const float* __restrict__ deg,
    const float* __restrict__ n1w, const float* __restrict__ n1b)
{
    __shared__ __align__(16) float sA[4096], sB[4096], sb[64];
    for (int t = threadIdx.x; t < 4096; t += 256) { sA[t] = n1w[t]; sB[t] = n1w[4096 + t]; }
    if (threadIdx.x < 64) sb[threadIdx.x] = n1b[threadIdx.x];
    __syncthreads();

    int i = blockIdx.x * 256 + threadIdx.x;
    if (i >= N_) return;

    float xi[64], ag[64];
    {
        const float4* px = reinterpret_cast<const float4*>(x + (size_t)i * 64);
        const float4* pa = reinterpret_cast<const float4*>(agg1 + (size_t)i * 64);
#pragma unroll
        for (int r = 0; r < 16; r++) {
            float4 v = px[r];
            xi[4 * r] = v.x; xi[4 * r + 1] = v.y; xi[4 * r + 2] = v.z; xi[4 * r + 3] = v.w;
            float4 a = pa[r];
            ag[4 * r] = a.x; ag[4 * r + 1] = a.y; ag[4 * r + 2] = a.z; ag[4 * r + 3] = a.w;
        }
    }
    float d = deg[i];

#pragma unroll
    for (int j = 0; j < 64; j += 4) {
        float sx = sb[j], sy = sb[j + 1], sz = sb[j + 2], sw_ = sb[j + 3];
        float gx = 0.f, gy = 0.f, gz = 0.f, gw = 0.f;
#pragma unroll
        for (int k = 0; k < 64; k++) {
            float4 wa = *reinterpret_cast<const float4*>(&sA[k * 64 + j]);
            float xv = xi[k];
            sx += xv * wa.x; sy += xv * wa.y; sz += xv * wa.z; sw_ += xv * wa.w;
            float4 wb = *reinterpret_cast<const float4*>(&sB[k * 64 + j]);
            float av = ag[k];
            gx += av * wb.x; gy += av * wb.y; gz += av * wb.z; gw += av * wb.w;
        }
        float4 o;
        o.x = leaky(d * sx + gx);
        o.y = leaky(d * sy + gy);
        o.z = leaky(d * sz + gz);
        o.w = leaky(d * sw_ + gw);
        *reinterpret_cast<float4*>(&agg1[(size_t)i * 64 + j]) = o;   // in-place h1
    }
}

// ---------------------------------------------------------------------------
// Node update conv2 + heads (mu/logvar/z) + pooled sums + graph node counts
// ---------------------------------------------------------------------------
__global__ __launch_bounds__(256) void node2_kernel(
    const float* __restrict__ h1, const float* __restrict__ agg2,
    const float* __restrict__ deg, const int* __restrict__ batch,
    const float* __restrict__ n2w, const float* __restrict__ n2b,
    const float* __restrict__ mu_w, const float* __restrict__ mu_b,
    const float* __restrict__ lv_w, const float* __restrict__ lv_b,
    float* __restrict__ out, float* __restrict__ sums, float* __restrict__ cnt)
{
    __shared__ __align__(16) float sA[4096], sB[4096], sb[64];
    __shared__ __align__(16) float sMu[2048], sLv[2048], sMb[32], sLb[32];
    for (int t = threadIdx.x; t < 4096; t += 256) { sA[t] = n2w[t]; sB[t] = n2w[4096 + t]; }
    for (int t = threadIdx.x; t < 2048; t += 256) { sMu[t] = mu_w[t]; sLv[t] = lv_w[t]; }
    if (threadIdx.x < 64) sb[threadIdx.x] = n2b[threadIdx.x];
    if (threadIdx.x < 32) { sMb[threadIdx.x] = mu_b[threadIdx.x]; sLb[threadIdx.x] = lv_b[threadIdx.x]; }
    __syncthreads();

    int i = blockIdx.x * 256 + threadIdx.x;
    if (i >= N_) return;

    float hi[64], ag[64];
    {
        const float4* ph = reinterpret_cast<const float4*>(h1 + (size_t)i * 64);
        const float4* pa = reinterpret_cast<const float4*>(agg2 + (size_t)i * 64);
#pragma unroll
        for (int r = 0; r < 16; r++) {
            float4 v = ph[r];
            hi[4 * r] = v.x; hi[4 * r + 1] = v.y; hi[4 * r + 2] = v.z; hi[4 * r + 3] = v.w;
            float4 a = pa[r];
            ag[4 * r] = a.x; ag[4 * r + 1] = a.y; ag[4 * r + 2] = a.z; ag[4 * r + 3] = a.w;
        }
    }
    float d = deg[i];

    float t2[64];
#pragma unroll
    for (int j = 0; j < 64; j += 4) {
        float sx = sb[j], sy = sb[j + 1], sz = sb[j + 2], sw_ = sb[j + 3];
        float gx = 0.f, gy = 0.f, gz = 0.f, gw = 0.f;
#pragma unroll
        for (int k = 0; k < 64; k++) {
            float4 wa = *reinterpret_cast<const float4*>(&sA[k * 64 + j]);
            float hv = hi[k];
            sx += hv * wa.x; sy += hv * wa.y; sz += hv * wa.z; sw_ += hv * wa.w;
            float4 wb = *reinterpret_cast<const float4*>(&sB[k * 64 + j]);
            float av = ag[k];
            gx += av * wb.x; gy += av * wb.y; gz += av * wb.z; gw += av * wb.w;
        }
        t2[j]     = leaky(d * sx + gx);
        t2[j + 1] = leaky(d * sy + gy);
        t2[j + 2] = leaky(d * sz + gz);
        t2[j + 3] = leaky(d * sw_ + gw);
    }

    int b = batch[i];
    atomicAdd(&cnt[b], 1.0f);
    // mu (= z) head + pooled sums
#pragma unroll
    for (int j = 0; j < 32; j += 4) {
        float ax = sMb[j], ay = sMb[j + 1], az = sMb[j + 2], aw = sMb[j + 3];
#pragma unroll
        for (int k = 0; k < 64; k++) {
            float4 w = *reinterpret_cast<const float4*>(&sMu[k * 32 + j]);
            float t = t2[k];
            ax += t * w.x; ay += t * w.y; az += t * w.z; aw += t * w.w;
        }
        float4 o; o.x = ax; o.y = ay; o.z = az; o.w = aw;
        *reinterpret_cast<float4*>(&out[(size_t)i * 32 + j]) = o;                    // z
        *reinterpret_cast<float4*>(&out[(size_t)N_ * 32 + (size_t)i * 32 + j]) = o;  // mu
        atomicAdd(&sums[b * 32 + j],     ax);
        atomicAdd(&sums[b * 32 + j + 1], ay);
        atomicAdd(&sums[b * 32 + j + 2], az);
        atomicAdd(&sums[b * 32 + j + 3], aw);
    }
    // logvar head
#pragma unroll
    for (int j = 0; j < 32; j += 4) {
        float ax = sLb[j], ay = sLb[j + 1], az = sLb[j + 2], aw = sLb[j + 3];
#pragma unroll
        for (int k = 0; k < 64; k++) {
            float4 w = *reinterpret_cast<const float4*>(&sLv[k * 32 + j]);
            float t = t2[k];
            ax += t * w.x; ay += t * w.y; az += t * w.z; aw += t * w.w;
        }
        float4 o; o.x = ax; o.y = ay; o.z = az; o.w = aw;
        *reinterpret_cast<float4*>(&out[2ull * N_ * 32 + (size_t)i * 32 + j]) = o;   // logvar
    }
}

// ---------------------------------------------------------------------------
// Pool: pooled mean + classifier (tiny)
// ---------------------------------------------------------------------------
__global__ void pool_kernel(const float* __restrict__ sums, const float* __restrict__ cnt,
                            const float* __restrict__ cls_w, const float* __restrict__ cls_b,
                            float* __restrict__ out)
{
    int g = threadIdx.x;  // 128 threads
    float ic = 1.0f / fmaxf(cnt[g], 1.0f);
    float p[32];
#pragma unroll
    for (int k = 0; k < 32; k++) p[k] = sums[g * 32 + k] * ic;
#pragma unroll
    for (int j = 0; j < 10; j++) {
        float acc = cls_b[j];
#pragma unroll
        for (int k = 0; k < 32; k++) acc += p[k] * cls_w[k * 10 + j];
        out[3ull * N_ * 32 + g * 10 + j] = acc;
    }
}

// ---------------------------------------------------------------------------
extern "C" void kernel_launch(void* const* d_in, const int* in_sizes, int n_in,
                              void* d_out, int out_size, void* d_ws, size_t ws_size,
                              hipStream_t stream)
{
    const float* x         = (const float*)d_in[0];
    const int*   ei        = (const int*)  d_in[1];
    const float* edge_attr = (const float*)d_in[2];
    const int*   batch     = (const int*)  d_in[3];
    const float* e1w1 = (const float*)d_in[4];
    const float* e1b1 = (const float*)d_in[5];
    const float* e1w2 = (const float*)d_in[6];
    const float* e1b2 = (const float*)d_in[7];
    const float* n1w  = (const float*)d_in[8];
    const float* n1b  = (const float*)d_in[9];
    const float* e2w1 = (const float*)d_in[10];
    const float* e2b1 = (const float*)d_in[11];
    const float* e2w2 = (const float*)d_in[12];
    const float* e2b2 = (const float*)d_in[13];
    const float* n2w  = (const float*)d_in[14];
    const float* n2b  = (const float*)d_in[15];
    const float* mu_w = (const float*)d_in[16];
    const float* mu_b = (const float*)d_in[17];
    const float* lv_w = (const float*)d_in[18];
    const float* lv_b = (const float*)d_in[19];
    const float* cls_w = (const float*)d_in[20];
    const float* cls_b = (const float*)d_in[21];

    float* out = (float*)d_out;
    float* ws  = (float*)d_ws;

    // ws layout (floats):
    float* deg  = ws;                              // N
    float* cnt  = ws + N_;                         // G
    float* sums = ws + N_ + G_;                    // G*32
    float* agg1 = sums + G_ * 32;                  // N*64  (becomes h1 in place)
    float* agg2 = agg1 + (size_t)N_ * 64;          // N*64

    size_t zero_floats = (size_t)N_ + G_ + G_ * 32 + 2ull * N_ * 64;
    hipMemsetAsync(d_ws, 0, zero_floats * sizeof(float), stream);

    edge_kernel<<<E_ / 512, 256, 0, stream>>>(edge_attr, ei,
                                              e1w1, e1b1, e1w2, e1b2,
                                              e2w1, e2b1, e2w2, e2b2,
                                              agg1, agg2, deg);
    node1_kernel<<<(N_ + 255) / 256, 256, 0, stream>>>(x, agg1, deg, n1w, n1b);
    node2_kernel<<<(N_ + 255) / 256, 256, 0, stream>>>(agg1, agg2, deg, batch,
                                                       n2w, n2b, mu_w, mu_b, lv_w, lv_b,
                                                       out, sums, cnt);
    pool_kernel<<<1, 128, 0, stream>>>(sums, cnt, cls_w, cls_b, out);
}